// Round 18
// baseline (1382.038 us; speedup 1.0000x reference)
//
#include <hip/hip_runtime.h>
#include <math.h>

typedef unsigned short u16;
typedef short s16x8 __attribute__((ext_vector_type(8)));
typedef float f32x4 __attribute__((ext_vector_type(4)));

#define NITER 32   // K=1024 / BK=32 k-tiles

// Pre-split, transposed weights: layout [kb 32][gate 5][j 512][k 32]
__device__ __align__(16) u16 g_Bhi[1024 * 2560];
__device__ __align__(16) u16 g_Blo[1024 * 2560];
// Pre-split leaf A panel: row i -> split emb[tokens[i]] (1024 u16 = 32 chunks of [16hi|16lo])
__device__ __align__(16) u16 g_Aleaf[(size_t)64 * 1024 * 1024];

__device__ __forceinline__ u16 f2bf(float x) {
    unsigned u = __float_as_uint(x);
    u += 0x7fffu + ((u >> 16) & 1u);       // RNE
    return (u16)(u >> 16);
}
__device__ __forceinline__ float bf2f(u16 h) { return __uint_as_float(((unsigned)h) << 16); }
__device__ __forceinline__ float sigm(float x) { return 1.0f / (1.0f + expf(-x)); }
__device__ __forceinline__ unsigned pk(u16 a, u16 b) { return (unsigned)a | ((unsigned)b << 16); }

// A staging: NON-TEMPORAL (aux=2 = NT CPol bit) -- A is read exactly once; keeps the
// reused B slice resident in each XCD's L2 (leaf FETCH showed ~475MB of B re-fetch).
__device__ __forceinline__ void gload16nt(const void* g, u16* l) {
    __builtin_amdgcn_global_load_lds(
        (const __attribute__((address_space(1))) void*)g,
        (__attribute__((address_space(3))) void*)(void*)l, 16, 0, 2);
}

// ---------------- weight split+transpose: W[k][col] f32 -> [kb][g][j][k] bf16 hi/lo ----------
__global__ __launch_bounds__(256)
void wsplit_kernel(const float* __restrict__ Wiou, const float* __restrict__ Wf)
{
    __shared__ float tile[32][65];
    const int kb = blockIdx.x;           // 0..31
    const int cb = blockIdx.y;           // 0..39
    const int t  = threadIdx.x;
    const int c0 = cb * 64;

    {
        const int kk  = t >> 3;
        const int cu0 = (t & 7) * 8;
        const int k   = kb * 32 + kk;
#pragma unroll
        for (int u = 0; u < 8; u++) {
            int c = c0 + cu0 + u;
            float v = (c < 1536) ? Wiou[(size_t)k * 1536 + c]
                                 : Wf[(size_t)k * 1024 + (c - 1536)];
            tile[kk][cu0 + u] = v;
        }
    }
    __syncthreads();
    {
        const int jl = t >> 2;
        const int kc = (t & 3) * 8;
        const int g  = c0 >> 9;
        const int j  = (c0 & 511) + jl;
        size_t dst = (((size_t)kb * 5 + g) * 512 + j) * 32 + kc;
        unsigned ph[4], pl[4];
#pragma unroll
        for (int u = 0; u < 4; u++) {
            float v0 = tile[kc + 2 * u][jl];
            float v1 = tile[kc + 2 * u + 1][jl];
            u16 h0 = f2bf(v0), h1 = f2bf(v1);
            u16 l0 = f2bf(v0 - bf2f(h0)), l1 = f2bf(v1 - bf2f(h1));
            ph[u] = pk(h0, h1);
            pl[u] = pk(l0, l1);
        }
        *(uint4*)(g_Bhi + dst) = make_uint4(ph[0], ph[1], ph[2], ph[3]);
        *(uint4*)(g_Blo + dst) = make_uint4(pl[0], pl[1], pl[2], pl[3]);
    }
}

// ---------------- leaf A gather+split ----------------
__global__ __launch_bounds__(256)
void leafgather_kernel(const int* __restrict__ tokens, const float* __restrict__ emb)
{
    const int gidx = blockIdx.x * 256 + threadIdx.x;   // chunk id
    const int row  = gidx >> 5;
    const int c    = gidx & 31;
    const int tok  = tokens[row];
    const float* src = emb + (size_t)tok * 512 + c * 16;
    u16* dst = g_Aleaf + (size_t)row * 1024 + c * 32;

    float4 f0 = *(const float4*)(src);
    float4 f1 = *(const float4*)(src + 4);
    float4 f2 = *(const float4*)(src + 8);
    float4 f3 = *(const float4*)(src + 12);
    float v[16] = {f0.x,f0.y,f0.z,f0.w, f1.x,f1.y,f1.z,f1.w,
                   f2.x,f2.y,f2.z,f2.w, f3.x,f3.y,f3.z,f3.w};
    unsigned ph[8], pl[8];
#pragma unroll
    for (int i = 0; i < 8; i++) {
        u16 h0 = f2bf(v[2*i]),   h1 = f2bf(v[2*i+1]);
        u16 l0 = f2bf(v[2*i]   - bf2f(h0));
        u16 l1 = f2bf(v[2*i+1] - bf2f(h1));
        ph[i] = pk(h0, h1);
        pl[i] = pk(l0, l1);
    }
    *(uint4*)(dst)      = make_uint4(ph[0], ph[1], ph[2], ph[3]);
    *(uint4*)(dst + 8)  = make_uint4(ph[4], ph[5], ph[6], ph[7]);
    *(uint4*)(dst + 16) = make_uint4(pl[0], pl[1], pl[2], pl[3]);
    *(uint4*)(dst + 24) = make_uint4(pl[4], pl[5], pl[6], pl[7]);
}

// ---------------- big levels (np>=64): R16 schedule + NT cache policy ----------------
template<bool LEAF>
__global__ __launch_bounds__(256, 2)
void level_big(const u16* __restrict__ Hcin, const float* __restrict__ Cc,
               const float* __restrict__ b_iou, const float* __restrict__ b_f,
               u16* __restrict__ Hp, float* __restrict__ Cp,
               int np, int lgnp)
{
    __shared__ __align__(16) u16 Ab0[8192];   // 16 KB: k-tiles {t0, t0+1}
    __shared__ __align__(16) u16 Ab1[8192];   // 16 KB: next window

    const u16* Hc = LEAF ? g_Aleaf : Hcin;

    const int tid = threadIdx.x;
    const int jg  = blockIdx.x;          // 0..7 -> XCD pinning via %8
    const int m0  = blockIdx.y * 64;
    const int j0  = jg * 64;
    const int nc  = np * 2;

    const int w    = tid >> 6;
    const int lane = tid & 63;
    const int il   = lane & 15;
    const int kq   = lane >> 4;
    const int wc   = w;                  // j sub-range wc*16 .. +15

    f32x4 acc[4][5];
#pragma unroll
    for (int rf = 0; rf < 4; rf++)
#pragma unroll
        for (int g = 0; g < 5; g++) acc[rf][g] = (f32x4)0.0f;

    const int bA  = m0 >> lgnp;
    const int pA0 = m0 & (np - 1);
    const char* A0u = (const char*)(Hc + ((size_t)bA * nc + 2 * pA0) * 1024);  // uniform
    const int rowS = tid >> 3;
    const int segS = (tid & 7) ^ (rowS & 7);
    const unsigned voffA = (unsigned)rowS * 4096u + (unsigned)segS * 16u;

    const int shi = ((kq >> 1) << 2) | (kq & 1);
    const int x7  = il & 7;
    const int aoh = il * 64 + ((shi ^ x7) * 8);
    const int aol = il * 64 + (((shi + 2) ^ x7) * 8);

    const char* BH0 = (const char*)(g_Bhi + (size_t)j0 * 32);
    const char* BL0 = (const char*)(g_Blo + (size_t)j0 * 32);
    unsigned vB[5];
#pragma unroll
    for (int g = 0; g < 5; g++)
        vB[g] = (unsigned)(((wc * 16 + il) * 32 + kq * 8) * 2 + g * 32768);

    s16x8 bh[5], bl[5];
    s16x8 ah[4], al[4];

#define STAGEA2(DST, t_)                                                       \
    {                                                                          \
        const char* ab = A0u + (size_t)(t_) * 128;                             \
        gload16nt(ab + voffA, (DST) + w * 512);                                \
        gload16nt(ab + 131072 + voffA, (DST) + 2048 + w * 512);                \
    }

#define LOADB_HI(t_)                                                           \
    {                                                                          \
        const char* bhp = BH0 + (size_t)(t_) * 163840;                         \
        _Pragma("unroll")                                                      \
        for (int g = 0; g < 5; g++) bh[g] = *(const s16x8*)(bhp + vB[g]);      \
    }

#define LOADB_LO(t_)                                                           \
    {                                                                          \
        const char* blp = BL0 + (size_t)(t_) * 163840;                         \
        _Pragma("unroll")                                                      \
        for (int g = 0; g < 5; g++) bl[g] = *(const s16x8*)(blp + vB[g]);      \
    }

#define READ_AH(ABASE)                                                         \
    {                                                                          \
        _Pragma("unroll")                                                      \
        for (int rf = 0; rf < 4; rf++)                                         \
            ah[rf] = *(const s16x8*)&(ABASE)[aoh + rf * 1024];                 \
    }

#define READ_AL(ABASE)                                                         \
    {                                                                          \
        _Pragma("unroll")                                                      \
        for (int rf = 0; rf < 4; rf++)                                         \
            al[rf] = *(const s16x8*)&(ABASE)[aol + rf * 1024];                 \
    }

#define MFMA_PASS(AREGS, BSET)                                                 \
    {                                                                          \
        __builtin_amdgcn_s_setprio(1);                                         \
        _Pragma("unroll")                                                      \
        for (int rf = 0; rf < 4; rf++)                                         \
            _Pragma("unroll")                                                  \
            for (int g = 0; g < 5; g++)                                        \
                acc[rf][g] = __builtin_amdgcn_mfma_f32_16x16x32_bf16(AREGS[rf], BSET[g], acc[rf][g], 0, 0, 0); \
        __builtin_amdgcn_s_setprio(0);                                         \
    }

#define WINDOW(ACUR, ANXT, t0_, more_)                                         \
    {                                                                          \
        if (more_) {                                                           \
            STAGEA2(ANXT, (t0_) + 2);                                          \
            STAGEA2((ANXT) + 4096, (t0_) + 3);                                 \
            __builtin_amdgcn_sched_barrier(0);                                 \
        }                                                                      \
        MFMA_PASS(ah, bh);                                                     \
        MFMA_PASS(al, bh);                                                     \
        LOADB_HI((t0_) + 1);                                                   \
        READ_AL((ACUR) + 4096);                                                \
        MFMA_PASS(ah, bl);                                                     \
        LOADB_LO((t0_) + 1);                                                   \
        READ_AH((ACUR) + 4096);                                                \
        MFMA_PASS(al, bh);                                                     \
        MFMA_PASS(ah, bh);                                                     \
        if (more_) LOADB_HI((t0_) + 2);                                        \
        MFMA_PASS(ah, bl);                                                     \
        if (more_) LOADB_LO((t0_) + 2);                                        \
        if (more_) {                                                           \
            asm volatile("s_waitcnt vmcnt(10)" ::: "memory");                  \
            __builtin_amdgcn_s_barrier();                                      \
            __builtin_amdgcn_sched_barrier(0);                                 \
            READ_AH(ANXT);                                                     \
            READ_AL(ANXT);                                                     \
        }                                                                      \
    }

    STAGEA2(Ab0, 0);
    STAGEA2(Ab0 + 4096, 1);
    __builtin_amdgcn_sched_barrier(0);
    LOADB_HI(0);
    LOADB_LO(0);
    asm volatile("s_waitcnt vmcnt(10)" ::: "memory");
    __builtin_amdgcn_s_barrier();
    __builtin_amdgcn_sched_barrier(0);
    READ_AH(Ab0);
    READ_AL(Ab0);

#pragma unroll 1
    for (int t0 = 0; t0 < NITER; t0 += 4) {
        WINDOW(Ab0, Ab1, t0, 1);
        WINDOW(Ab1, Ab0, t0 + 2, (t0 + 4 < NITER));
    }
#undef STAGEA2
#undef LOADB_HI
#undef LOADB_LO
#undef READ_AH
#undef READ_AL
#undef MFMA_PASS
#undef WINDOW

    const int jglob = j0 + wc * 16 + il;
    const float bi  = b_iou[jglob];
    const float bo_ = b_iou[512 + jglob];
    const float bu  = b_iou[1024 + jglob];
    const float bfl = b_f[jglob];
    const float bfr = b_f[512 + jglob];

#pragma unroll
    for (int rf = 0; rf < 4; rf++) {
#pragma unroll
        for (int r = 0; r < 4; r++) {
            const int m  = m0 + rf * 16 + kq * 4 + r;
            const int b  = m >> lgnp;
            const int p  = m & (np - 1);
            float i_ = acc[rf][0][r] + bi;
            float o_ = acc[rf][1][r] + bo_;
            float u_ = acc[rf][2][r] + bu;
            float fl = sigm(acc[rf][3][r] + bfl);
            float fr = sigm(acc[rf][4][r] + bfr);
            float cl = 0.0f, cr_ = 0.0f;
            if (!LEAF) {
                size_t cb_ = ((size_t)b * nc + 2 * p) * 512 + jglob;
                cl  = Cc[cb_];
                cr_ = Cc[cb_ + 512];
            }
            float cn = sigm(i_) * tanhf(u_) + fl * cl + fr * cr_;
            float hn = sigm(o_) * tanhf(cn);
            size_t prow = (size_t)b * np + p;
            u16 hh  = f2bf(hn);
            u16 hlo = f2bf(hn - bf2f(hh));
            __builtin_nontemporal_store(hh,  &Hp[prow * 1024 + (size_t)(jg * 4 + wc) * 32 + il]);
            __builtin_nontemporal_store(hlo, &Hp[prow * 1024 + (size_t)(jg * 4 + wc) * 32 + 16 + il]);
            __builtin_nontemporal_store(cn,  &Cp[prow * 512 + jglob]);
        }
    }
}

// ---------------- small levels (np<64): R17 small2 + NT cache policy ----------------
__global__ __launch_bounds__(256, 2)
void level_small2(const u16* __restrict__ Hc, const float* __restrict__ Cc,
                  const float* __restrict__ b_iou, const float* __restrict__ b_f,
                  u16* __restrict__ Hp, float* __restrict__ Cp,
                  int np, int lgnp)
{
    __shared__ __align__(16) u16 Ab0[8192];
    __shared__ __align__(16) u16 Ab1[8192];

    const int tid = threadIdx.x;
    const int jg  = blockIdx.x;          // 0..31, one 16-d chunk; XCD = jg % 8
    const int m0  = blockIdx.y * 64;
    const int j0  = jg * 16;
    const int nc  = np * 2;

    const int w    = tid >> 6;           // wave -> row quarter
    const int lane = tid & 63;
    const int il   = lane & 15;
    const int kq   = lane >> 4;

    f32x4 acc[5];
#pragma unroll
    for (int g = 0; g < 5; g++) acc[g] = (f32x4)0.0f;

    const char* A0u = (const char*)(Hc + (size_t)m0 * 2048);   // globally contiguous rows
    const int rowS = tid >> 3;
    const int segS = (tid & 7) ^ (rowS & 7);
    const unsigned voffA = (unsigned)rowS * 4096u + (unsigned)segS * 16u;

    const int shi = ((kq >> 1) << 2) | (kq & 1);
    const int x7  = il & 7;
    const int aoh = (w * 16 + il) * 64 + ((shi ^ x7) * 8);
    const int aol = (w * 16 + il) * 64 + (((shi + 2) ^ x7) * 8);

    const char* BH0 = (const char*)(g_Bhi + (size_t)j0 * 32);
    const char* BL0 = (const char*)(g_Blo + (size_t)j0 * 32);
    unsigned vB[5];
#pragma unroll
    for (int g = 0; g < 5; g++)
        vB[g] = (unsigned)((il * 32 + kq * 8) * 2 + g * 32768);

    s16x8 bh[5], bl[5];
    s16x8 ah, al;

#define SSTAGEA2(DST, t_)                                                      \
    {                                                                          \
        const char* ab = A0u + (size_t)(t_) * 128;                             \
        gload16nt(ab + voffA, (DST) + w * 512);                                \
        gload16nt(ab + 131072 + voffA, (DST) + 2048 + w * 512);                \
    }

#define SLOADB_HI(t_)                                                          \
    {                                                                          \
        const char* bhp = BH0 + (size_t)(t_) * 163840;                         \
        _Pragma("unroll")                                                      \
        for (int g = 0; g < 5; g++) bh[g] = *(const s16x8*)(bhp + vB[g]);      \
    }

#define SLOADB_LO(t_)                                                          \
    {                                                                          \
        const char* blp = BL0 + (size_t)(t_) * 163840;                         \
        _Pragma("unroll")                                                      \
        for (int g = 0; g < 5; g++) bl[g] = *(const s16x8*)(blp + vB[g]);      \
    }

#define SREAD_AH(ABASE)  { ah = *(const s16x8*)&(ABASE)[aoh]; }
#define SREAD_AL(ABASE)  { al = *(const s16x8*)&(ABASE)[aol]; }

#define SMFMA_PASS(AREG, BSET)                                                 \
    {                                                                          \
        _Pragma("unroll")                                                      \
        for (int g = 0; g < 5; g++)                                            \
            acc[g] = __builtin_amdgcn_mfma_f32_16x16x32_bf16(AREG, BSET[g], acc[g], 0, 0, 0); \
    }

#define SWINDOW(ACUR, ANXT, t0_, more_)                                        \
    {                                                                          \
        if (more_) {                                                           \
            SSTAGEA2(ANXT, (t0_) + 2);                                         \
            SSTAGEA2((ANXT) + 4096, (t0_) + 3);                                \
            __builtin_amdgcn_sched_barrier(0);                                 \
        }                                                                      \
        SMFMA_PASS(ah, bh);                                                    \
        SMFMA_PASS(al, bh);                                                    \
        SLOADB_HI((t0_) + 1);                                                  \
        SREAD_AL((ACUR) + 4096);                                               \
        SMFMA_PASS(ah, bl);                                                    \
        SLOADB_LO((t0_) + 1);                                                  \
        SREAD_AH((ACUR) + 4096);                                               \
        SMFMA_PASS(al, bh);                                                    \
        SMFMA_PASS(ah, bh);                                                    \
        if (more_) SLOADB_HI((t0_) + 2);                                       \
        SMFMA_PASS(ah, bl);                                                    \
        if (more_) SLOADB_LO((t0_) + 2);                                       \
        if (more_) {                                                           \
            asm volatile("s_waitcnt vmcnt(10)" ::: "memory");                  \
            __builtin_amdgcn_s_barrier();                                      \
            __builtin_amdgcn_sched_barrier(0);                                 \
            SREAD_AH(ANXT);                                                    \
            SREAD_AL(ANXT);                                                    \
        }                                                                      \
    }

    SSTAGEA2(Ab0, 0);
    SSTAGEA2(Ab0 + 4096, 1);
    __builtin_amdgcn_sched_barrier(0);
    SLOADB_HI(0);
    SLOADB_LO(0);
    asm volatile("s_waitcnt vmcnt(10)" ::: "memory");
    __builtin_amdgcn_s_barrier();
    __builtin_amdgcn_sched_barrier(0);
    SREAD_AH(Ab0);
    SREAD_AL(Ab0);

#pragma unroll 1
    for (int t0 = 0; t0 < NITER; t0 += 4) {
        SWINDOW(Ab0, Ab1, t0, 1);
        SWINDOW(Ab1, Ab0, t0 + 2, (t0 + 4 < NITER));
    }
#undef SSTAGEA2
#undef SLOADB_HI
#undef SLOADB_LO
#undef SREAD_AH
#undef SREAD_AL
#undef SMFMA_PASS
#undef SWINDOW

    // ---- fused LSTM epilogue ----
    const int jglob = j0 + il;
    const float bi  = b_iou[jglob];
    const float bo_ = b_iou[512 + jglob];
    const float bu  = b_iou[1024 + jglob];
    const float bfl = b_f[jglob];
    const float bfr = b_f[512 + jglob];

#pragma unroll
    for (int r = 0; r < 4; r++) {
        const int m = m0 + w * 16 + kq * 4 + r;
        const int b = m >> lgnp;
        const int p = m & (np - 1);
        float i_ = acc[0][r] + bi;
        float o_ = acc[1][r] + bo_;
        float u_ = acc[2][r] + bu;
        float fl = sigm(acc[3][r] + bfl);
        float fr = sigm(acc[4][r] + bfr);
        size_t cb_ = ((size_t)b * nc + 2 * p) * 512 + jglob;
        float cl  = Cc[cb_];
        float cr_ = Cc[cb_ + 512];
        float cn = sigm(i_) * tanhf(u_) + fl * cl + fr * cr_;
        float hn = sigm(o_) * tanhf(cn);
        size_t prow = (size_t)b * np + p;
        u16 hh  = f2bf(hn);
        u16 hlo = f2bf(hn - bf2f(hh));
        __builtin_nontemporal_store(hh,  &Hp[prow * 1024 + (size_t)jg * 32 + il]);
        __builtin_nontemporal_store(hlo, &Hp[prow * 1024 + (size_t)jg * 32 + 16 + il]);
        __builtin_nontemporal_store(cn,  &Cp[prow * 512 + jglob]);
    }
}

// ---------------- out[b][c] = sum_d h_root[b][d] * W_out[d][c] ----------------
__global__ __launch_bounds__(256)
void out_kernel(const u16* __restrict__ Hroot, const float* __restrict__ W_out,
                float* __restrict__ out)
{
    const int b = blockIdx.x;
    const int tid = threadIdx.x;
    float s0 = 0.f, s1 = 0.f;
    for (int d = tid; d < 512; d += 256) {
        const u16* row = Hroot + (size_t)b * 1024 + (d >> 4) * 32 + (d & 15);
        float h = bf2f(row[0]) + bf2f(row[16]);
        s0 = fmaf(h, W_out[d * 2 + 0], s0);
        s1 = fmaf(h, W_out[d * 2 + 1], s1);
    }
#pragma unroll
    for (int off = 32; off > 0; off >>= 1) {
        s0 += __shfl_down(s0, off, 64);
        s1 += __shfl_down(s1, off, 64);
    }
    __shared__ float red[2][4];
    const int wave = tid >> 6;
    if ((tid & 63) == 0) { red[0][wave] = s0; red[1][wave] = s1; }
    __syncthreads();
    if (tid == 0) {
        float t0 = 0.f, t1 = 0.f;
#pragma unroll
        for (int wv = 0; wv < 4; wv++) { t0 += red[0][wv]; t1 += red[1][wv]; }
        out[b * 2 + 0] = t0;
        out[b * 2 + 1] = t1;
    }
}

extern "C" void kernel_launch(void* const* d_in, const int* in_sizes, int n_in,
                              void* d_out, int out_size, void* d_ws, size_t ws_size,
                              hipStream_t stream)
{
    const int*   tokens = (const int*)  d_in[0];
    const float* emb    = (const float*)d_in[1];
    const float* W_iou  = (const float*)d_in[2];
    const float* b_iou  = (const float*)d_in[3];
    const float* W_f    = (const float*)d_in[4];
    const float* b_f    = (const float*)d_in[5];
    const float* W_out  = (const float*)d_in[6];
    float* out = (float*)d_out;

    // ws layout (201.3 MB, proven):
    u16*   H0 = (u16*)d_ws;
    float* C0 = (float*)(H0 + (size_t)512 * 64 * 1024);
    u16*   H1 = (u16*)(C0 + (size_t)512 * 64 * 512);
    float* C1 = (float*)(H1 + (size_t)256 * 64 * 1024);

    wsplit_kernel<<<dim3(32, 40), 256, 0, stream>>>(W_iou, W_f);
    leafgather_kernel<<<8192, 256, 0, stream>>>(tokens, emb);

    // level 9: leaves -> 512 parents (A = g_Aleaf, c = 0)
    level_big<true><<<dim3(8, 512), 256, 0, stream>>>(
        nullptr, nullptr, b_iou, b_f, H0, C0, 512, 9);

    u16* Hc = H0;  float* Cc = C0;
    u16* Hp = H1;  float* Cp = C1;
    for (int L = 8; L >= 0; L--) {
        const int np = 1 << L;
        if (np >= 64) {
            level_big<false><<<dim3(8, np), 256, 0, stream>>>(
                Hc, Cc, b_iou, b_f, Hp, Cp, np, L);
        } else {
            level_small2<<<dim3(32, np), 256, 0, stream>>>(
                Hc, Cc, b_iou, b_f, Hp, Cp, np, L);
        }
        u16* tH = Hc; Hc = Hp; Hp = tH;
        float* tC = Cc; Cc = Cp; Cp = tC;
    }

    out_kernel<<<64, 256, 0, stream>>>(Hc, W_out, out);
}

// Round 19
// 1331.882 us; speedup vs baseline: 1.0377x; 1.0377x over previous
//
#include <hip/hip_runtime.h>
#include <math.h>

typedef unsigned short u16;
typedef short s16x8 __attribute__((ext_vector_type(8)));
typedef float f32x4 __attribute__((ext_vector_type(4)));

#define NITER 32   // K=1024 / BK=32 k-tiles

// Pre-split, transposed weights: layout [kb 32][gate 5][j 512][k 32]
__device__ __align__(16) u16 g_Bhi[1024 * 2560];
__device__ __align__(16) u16 g_Blo[1024 * 2560];
// Pre-split leaf A panel: row i -> split emb[tokens[i]] (1024 u16 = 32 chunks of [16hi|16lo])
__device__ __align__(16) u16 g_Aleaf[(size_t)64 * 1024 * 1024];

__device__ __forceinline__ u16 f2bf(float x) {
    unsigned u = __float_as_uint(x);
    u += 0x7fffu + ((u >> 16) & 1u);       // RNE
    return (u16)(u >> 16);
}
__device__ __forceinline__ float bf2f(u16 h) { return __uint_as_float(((unsigned)h) << 16); }
__device__ __forceinline__ float sigm(float x) { return 1.0f / (1.0f + expf(-x)); }
__device__ __forceinline__ unsigned pk(u16 a, u16 b) { return (unsigned)a | ((unsigned)b << 16); }

// A staging: NT bit (aux=2) -- A is read exactly once; goal: keep the reused B slice
// resident in each XCD's L2. Stores stay on the normal cached path (R18 showed NT
// stores of scattered u16 cause sub-line HBM RMW: +FETCH +WRITE).
__device__ __forceinline__ void gload16nt(const void* g, u16* l) {
    __builtin_amdgcn_global_load_lds(
        (const __attribute__((address_space(1))) void*)g,
        (__attribute__((address_space(3))) void*)(void*)l, 16, 0, 2);
}

// ---------------- weight split+transpose: W[k][col] f32 -> [kb][g][j][k] bf16 hi/lo ----------
__global__ __launch_bounds__(256)
void wsplit_kernel(const float* __restrict__ Wiou, const float* __restrict__ Wf)
{
    __shared__ float tile[32][65];
    const int kb = blockIdx.x;           // 0..31
    const int cb = blockIdx.y;           // 0..39
    const int t  = threadIdx.x;
    const int c0 = cb * 64;

    {
        const int kk  = t >> 3;
        const int cu0 = (t & 7) * 8;
        const int k   = kb * 32 + kk;
#pragma unroll
        for (int u = 0; u < 8; u++) {
            int c = c0 + cu0 + u;
            float v = (c < 1536) ? Wiou[(size_t)k * 1536 + c]
                                 : Wf[(size_t)k * 1024 + (c - 1536)];
            tile[kk][cu0 + u] = v;
        }
    }
    __syncthreads();
    {
        const int jl = t >> 2;
        const int kc = (t & 3) * 8;
        const int g  = c0 >> 9;
        const int j  = (c0 & 511) + jl;
        size_t dst = (((size_t)kb * 5 + g) * 512 + j) * 32 + kc;
        unsigned ph[4], pl[4];
#pragma unroll
        for (int u = 0; u < 4; u++) {
            float v0 = tile[kc + 2 * u][jl];
            float v1 = tile[kc + 2 * u + 1][jl];
            u16 h0 = f2bf(v0), h1 = f2bf(v1);
            u16 l0 = f2bf(v0 - bf2f(h0)), l1 = f2bf(v1 - bf2f(h1));
            ph[u] = pk(h0, h1);
            pl[u] = pk(l0, l1);
        }
        *(uint4*)(g_Bhi + dst) = make_uint4(ph[0], ph[1], ph[2], ph[3]);
        *(uint4*)(g_Blo + dst) = make_uint4(pl[0], pl[1], pl[2], pl[3]);
    }
}

// ---------------- leaf A gather+split ----------------
__global__ __launch_bounds__(256)
void leafgather_kernel(const int* __restrict__ tokens, const float* __restrict__ emb)
{
    const int gidx = blockIdx.x * 256 + threadIdx.x;   // chunk id
    const int row  = gidx >> 5;
    const int c    = gidx & 31;
    const int tok  = tokens[row];
    const float* src = emb + (size_t)tok * 512 + c * 16;
    u16* dst = g_Aleaf + (size_t)row * 1024 + c * 32;

    float4 f0 = *(const float4*)(src);
    float4 f1 = *(const float4*)(src + 4);
    float4 f2 = *(const float4*)(src + 8);
    float4 f3 = *(const float4*)(src + 12);
    float v[16] = {f0.x,f0.y,f0.z,f0.w, f1.x,f1.y,f1.z,f1.w,
                   f2.x,f2.y,f2.z,f2.w, f3.x,f3.y,f3.z,f3.w};
    unsigned ph[8], pl[8];
#pragma unroll
    for (int i = 0; i < 8; i++) {
        u16 h0 = f2bf(v[2*i]),   h1 = f2bf(v[2*i+1]);
        u16 l0 = f2bf(v[2*i]   - bf2f(h0));
        u16 l1 = f2bf(v[2*i+1] - bf2f(h1));
        ph[i] = pk(h0, h1);
        pl[i] = pk(l0, l1);
    }
    *(uint4*)(dst)      = make_uint4(ph[0], ph[1], ph[2], ph[3]);
    *(uint4*)(dst + 8)  = make_uint4(ph[4], ph[5], ph[6], ph[7]);
    *(uint4*)(dst + 16) = make_uint4(pl[0], pl[1], pl[2], pl[3]);
    *(uint4*)(dst + 24) = make_uint4(pl[4], pl[5], pl[6], pl[7]);
}

// ---------------- big levels (np>=64): R16 schedule + NT A-loads (stores normal) ----------
template<bool LEAF>
__global__ __launch_bounds__(256, 2)
void level_big(const u16* __restrict__ Hcin, const float* __restrict__ Cc,
               const float* __restrict__ b_iou, const float* __restrict__ b_f,
               u16* __restrict__ Hp, float* __restrict__ Cp,
               int np, int lgnp)
{
    __shared__ __align__(16) u16 Ab0[8192];   // 16 KB: k-tiles {t0, t0+1}
    __shared__ __align__(16) u16 Ab1[8192];   // 16 KB: next window

    const u16* Hc = LEAF ? g_Aleaf : Hcin;

    const int tid = threadIdx.x;
    const int jg  = blockIdx.x;          // 0..7 -> XCD pinning via %8
    const int m0  = blockIdx.y * 64;
    const int j0  = jg * 64;
    const int nc  = np * 2;

    const int w    = tid >> 6;
    const int lane = tid & 63;
    const int il   = lane & 15;
    const int kq   = lane >> 4;
    const int wc   = w;                  // j sub-range wc*16 .. +15

    f32x4 acc[4][5];
#pragma unroll
    for (int rf = 0; rf < 4; rf++)
#pragma unroll
        for (int g = 0; g < 5; g++) acc[rf][g] = (f32x4)0.0f;

    const int bA  = m0 >> lgnp;
    const int pA0 = m0 & (np - 1);
    const char* A0u = (const char*)(Hc + ((size_t)bA * nc + 2 * pA0) * 1024);  // uniform
    const int rowS = tid >> 3;
    const int segS = (tid & 7) ^ (rowS & 7);
    const unsigned voffA = (unsigned)rowS * 4096u + (unsigned)segS * 16u;

    const int shi = ((kq >> 1) << 2) | (kq & 1);
    const int x7  = il & 7;
    const int aoh = il * 64 + ((shi ^ x7) * 8);
    const int aol = il * 64 + (((shi + 2) ^ x7) * 8);

    const char* BH0 = (const char*)(g_Bhi + (size_t)j0 * 32);
    const char* BL0 = (const char*)(g_Blo + (size_t)j0 * 32);
    unsigned vB[5];
#pragma unroll
    for (int g = 0; g < 5; g++)
        vB[g] = (unsigned)(((wc * 16 + il) * 32 + kq * 8) * 2 + g * 32768);

    s16x8 bh[5], bl[5];
    s16x8 ah[4], al[4];

#define STAGEA2(DST, t_)                                                       \
    {                                                                          \
        const char* ab = A0u + (size_t)(t_) * 128;                             \
        gload16nt(ab + voffA, (DST) + w * 512);                                \
        gload16nt(ab + 131072 + voffA, (DST) + 2048 + w * 512);                \
    }

#define LOADB_HI(t_)                                                           \
    {                                                                          \
        const char* bhp = BH0 + (size_t)(t_) * 163840;                         \
        _Pragma("unroll")                                                      \
        for (int g = 0; g < 5; g++) bh[g] = *(const s16x8*)(bhp + vB[g]);      \
    }

#define LOADB_LO(t_)                                                           \
    {                                                                          \
        const char* blp = BL0 + (size_t)(t_) * 163840;                         \
        _Pragma("unroll")                                                      \
        for (int g = 0; g < 5; g++) bl[g] = *(const s16x8*)(blp + vB[g]);      \
    }

#define READ_AH(ABASE)                                                         \
    {                                                                          \
        _Pragma("unroll")                                                      \
        for (int rf = 0; rf < 4; rf++)                                         \
            ah[rf] = *(const s16x8*)&(ABASE)[aoh + rf * 1024];                 \
    }

#define READ_AL(ABASE)                                                         \
    {                                                                          \
        _Pragma("unroll")                                                      \
        for (int rf = 0; rf < 4; rf++)                                         \
            al[rf] = *(const s16x8*)&(ABASE)[aol + rf * 1024];                 \
    }

#define MFMA_PASS(AREGS, BSET)                                                 \
    {                                                                          \
        __builtin_amdgcn_s_setprio(1);                                         \
        _Pragma("unroll")                                                      \
        for (int rf = 0; rf < 4; rf++)                                         \
            _Pragma("unroll")                                                  \
            for (int g = 0; g < 5; g++)                                        \
                acc[rf][g] = __builtin_amdgcn_mfma_f32_16x16x32_bf16(AREGS[rf], BSET[g], acc[rf][g], 0, 0, 0); \
        __builtin_amdgcn_s_setprio(0);                                         \
    }

#define WINDOW(ACUR, ANXT, t0_, more_)                                         \
    {                                                                          \
        if (more_) {                                                           \
            STAGEA2(ANXT, (t0_) + 2);                                          \
            STAGEA2((ANXT) + 4096, (t0_) + 3);                                 \
            __builtin_amdgcn_sched_barrier(0);                                 \
        }                                                                      \
        MFMA_PASS(ah, bh);                                                     \
        MFMA_PASS(al, bh);                                                     \
        LOADB_HI((t0_) + 1);                                                   \
        READ_AL((ACUR) + 4096);                                                \
        MFMA_PASS(ah, bl);                                                     \
        LOADB_LO((t0_) + 1);                                                   \
        READ_AH((ACUR) + 4096);                                                \
        MFMA_PASS(al, bh);                                                     \
        MFMA_PASS(ah, bh);                                                     \
        if (more_) LOADB_HI((t0_) + 2);                                        \
        MFMA_PASS(ah, bl);                                                     \
        if (more_) LOADB_LO((t0_) + 2);                                        \
        if (more_) {                                                           \
            asm volatile("s_waitcnt vmcnt(10)" ::: "memory");                  \
            __builtin_amdgcn_s_barrier();                                      \
            __builtin_amdgcn_sched_barrier(0);                                 \
            READ_AH(ANXT);                                                     \
            READ_AL(ANXT);                                                     \
        }                                                                      \
    }

    STAGEA2(Ab0, 0);
    STAGEA2(Ab0 + 4096, 1);
    __builtin_amdgcn_sched_barrier(0);
    LOADB_HI(0);
    LOADB_LO(0);
    asm volatile("s_waitcnt vmcnt(10)" ::: "memory");
    __builtin_amdgcn_s_barrier();
    __builtin_amdgcn_sched_barrier(0);
    READ_AH(Ab0);
    READ_AL(Ab0);

#pragma unroll 1
    for (int t0 = 0; t0 < NITER; t0 += 4) {
        WINDOW(Ab0, Ab1, t0, 1);
        WINDOW(Ab1, Ab0, t0 + 2, (t0 + 4 < NITER));
    }
#undef STAGEA2
#undef LOADB_HI
#undef LOADB_LO
#undef READ_AH
#undef READ_AL
#undef MFMA_PASS
#undef WINDOW

    const int jglob = j0 + wc * 16 + il;
    const float bi  = b_iou[jglob];
    const float bo_ = b_iou[512 + jglob];
    const float bu  = b_iou[1024 + jglob];
    const float bfl = b_f[jglob];
    const float bfr = b_f[512 + jglob];

#pragma unroll
    for (int rf = 0; rf < 4; rf++) {
#pragma unroll
        for (int r = 0; r < 4; r++) {
            const int m  = m0 + rf * 16 + kq * 4 + r;
            const int b  = m >> lgnp;
            const int p  = m & (np - 1);
            float i_ = acc[rf][0][r] + bi;
            float o_ = acc[rf][1][r] + bo_;
            float u_ = acc[rf][2][r] + bu;
            float fl = sigm(acc[rf][3][r] + bfl);
            float fr = sigm(acc[rf][4][r] + bfr);
            float cl = 0.0f, cr_ = 0.0f;
            if (!LEAF) {
                size_t cb_ = ((size_t)b * nc + 2 * p) * 512 + jglob;
                cl  = Cc[cb_];
                cr_ = Cc[cb_ + 512];
            }
            float cn = sigm(i_) * tanhf(u_) + fl * cl + fr * cr_;
            float hn = sigm(o_) * tanhf(cn);
            size_t prow = (size_t)b * np + p;
            u16 hh  = f2bf(hn);
            u16 hlo = f2bf(hn - bf2f(hh));
            Hp[prow * 1024 + (size_t)(jg * 4 + wc) * 32 + il]      = hh;
            Hp[prow * 1024 + (size_t)(jg * 4 + wc) * 32 + 16 + il] = hlo;
            Cp[prow * 512 + jglob] = cn;
        }
    }
}

// ---------------- small levels (np<64): R17 small2 + NT A-loads (stores normal) ----------
__global__ __launch_bounds__(256, 2)
void level_small2(const u16* __restrict__ Hc, const float* __restrict__ Cc,
                  const float* __restrict__ b_iou, const float* __restrict__ b_f,
                  u16* __restrict__ Hp, float* __restrict__ Cp,
                  int np, int lgnp)
{
    __shared__ __align__(16) u16 Ab0[8192];
    __shared__ __align__(16) u16 Ab1[8192];

    const int tid = threadIdx.x;
    const int jg  = blockIdx.x;          // 0..31, one 16-d chunk; XCD = jg % 8
    const int m0  = blockIdx.y * 64;
    const int j0  = jg * 16;
    const int nc  = np * 2;

    const int w    = tid >> 6;           // wave -> row quarter
    const int lane = tid & 63;
    const int il   = lane & 15;
    const int kq   = lane >> 4;

    f32x4 acc[5];
#pragma unroll
    for (int g = 0; g < 5; g++) acc[g] = (f32x4)0.0f;

    const char* A0u = (const char*)(Hc + (size_t)m0 * 2048);   // globally contiguous rows
    const int rowS = tid >> 3;
    const int segS = (tid & 7) ^ (rowS & 7);
    const unsigned voffA = (unsigned)rowS * 4096u + (unsigned)segS * 16u;

    const int shi = ((kq >> 1) << 2) | (kq & 1);
    const int x7  = il & 7;
    const int aoh = (w * 16 + il) * 64 + ((shi ^ x7) * 8);
    const int aol = (w * 16 + il) * 64 + (((shi + 2) ^ x7) * 8);

    const char* BH0 = (const char*)(g_Bhi + (size_t)j0 * 32);
    const char* BL0 = (const char*)(g_Blo + (size_t)j0 * 32);
    unsigned vB[5];
#pragma unroll
    for (int g = 0; g < 5; g++)
        vB[g] = (unsigned)((il * 32 + kq * 8) * 2 + g * 32768);

    s16x8 bh[5], bl[5];
    s16x8 ah, al;

#define SSTAGEA2(DST, t_)                                                      \
    {                                                                          \
        const char* ab = A0u + (size_t)(t_) * 128;                             \
        gload16nt(ab + voffA, (DST) + w * 512);                                \
        gload16nt(ab + 131072 + voffA, (DST) + 2048 + w * 512);                \
    }

#define SLOADB_HI(t_)                                                          \
    {                                                                          \
        const char* bhp = BH0 + (size_t)(t_) * 163840;                         \
        _Pragma("unroll")                                                      \
        for (int g = 0; g < 5; g++) bh[g] = *(const s16x8*)(bhp + vB[g]);      \
    }

#define SLOADB_LO(t_)                                                          \
    {                                                                          \
        const char* blp = BL0 + (size_t)(t_) * 163840;                         \
        _Pragma("unroll")                                                      \
        for (int g = 0; g < 5; g++) bl[g] = *(const s16x8*)(blp + vB[g]);      \
    }

#define SREAD_AH(ABASE)  { ah = *(const s16x8*)&(ABASE)[aoh]; }
#define SREAD_AL(ABASE)  { al = *(const s16x8*)&(ABASE)[aol]; }

#define SMFMA_PASS(AREG, BSET)                                                 \
    {                                                                          \
        _Pragma("unroll")                                                      \
        for (int g = 0; g < 5; g++)                                            \
            acc[g] = __builtin_amdgcn_mfma_f32_16x16x32_bf16(AREG, BSET[g], acc[g], 0, 0, 0); \
    }

#define SWINDOW(ACUR, ANXT, t0_, more_)                                        \
    {                                                                          \
        if (more_) {                                                           \
            SSTAGEA2(ANXT, (t0_) + 2);                                         \
            SSTAGEA2((ANXT) + 4096, (t0_) + 3);                                \
            __builtin_amdgcn_sched_barrier(0);                                 \
        }                                                                      \
        SMFMA_PASS(ah, bh);                                                    \
        SMFMA_PASS(al, bh);                                                    \
        SLOADB_HI((t0_) + 1);                                                  \
        SREAD_AL((ACUR) + 4096);                                               \
        SMFMA_PASS(ah, bl);                                                    \
        SLOADB_LO((t0_) + 1);                                                  \
        SREAD_AH((ACUR) + 4096);                                               \
        SMFMA_PASS(al, bh);                                                    \
        SMFMA_PASS(ah, bh);                                                    \
        if (more_) SLOADB_HI((t0_) + 2);                                       \
        SMFMA_PASS(ah, bl);                                                    \
        if (more_) SLOADB_LO((t0_) + 2);                                       \
        if (more_) {                                                           \
            asm volatile("s_waitcnt vmcnt(10)" ::: "memory");                  \
            __builtin_amdgcn_s_barrier();                                      \
            __builtin_amdgcn_sched_barrier(0);                                 \
            SREAD_AH(ANXT);                                                    \
            SREAD_AL(ANXT);                                                    \
        }                                                                      \
    }

    SSTAGEA2(Ab0, 0);
    SSTAGEA2(Ab0 + 4096, 1);
    __builtin_amdgcn_sched_barrier(0);
    SLOADB_HI(0);
    SLOADB_LO(0);
    asm volatile("s_waitcnt vmcnt(10)" ::: "memory");
    __builtin_amdgcn_s_barrier();
    __builtin_amdgcn_sched_barrier(0);
    SREAD_AH(Ab0);
    SREAD_AL(Ab0);

#pragma unroll 1
    for (int t0 = 0; t0 < NITER; t0 += 4) {
        SWINDOW(Ab0, Ab1, t0, 1);
        SWINDOW(Ab1, Ab0, t0 + 2, (t0 + 4 < NITER));
    }
#undef SSTAGEA2
#undef SLOADB_HI
#undef SLOADB_LO
#undef SREAD_AH
#undef SREAD_AL
#undef SMFMA_PASS
#undef SWINDOW

    // ---- fused LSTM epilogue ----
    const int jglob = j0 + il;
    const float bi  = b_iou[jglob];
    const float bo_ = b_iou[512 + jglob];
    const float bu  = b_iou[1024 + jglob];
    const float bfl = b_f[jglob];
    const float bfr = b_f[512 + jglob];

#pragma unroll
    for (int r = 0; r < 4; r++) {
        const int m = m0 + w * 16 + kq * 4 + r;
        const int b = m >> lgnp;
        const int p = m & (np - 1);
        float i_ = acc[0][r] + bi;
        float o_ = acc[1][r] + bo_;
        float u_ = acc[2][r] + bu;
        float fl = sigm(acc[3][r] + bfl);
        float fr = sigm(acc[4][r] + bfr);
        size_t cb_ = ((size_t)b * nc + 2 * p) * 512 + jglob;
        float cl  = Cc[cb_];
        float cr_ = Cc[cb_ + 512];
        float cn = sigm(i_) * tanhf(u_) + fl * cl + fr * cr_;
        float hn = sigm(o_) * tanhf(cn);
        size_t prow = (size_t)b * np + p;
        u16 hh  = f2bf(hn);
        u16 hlo = f2bf(hn - bf2f(hh));
        Hp[prow * 1024 + (size_t)jg * 32 + il]      = hh;
        Hp[prow * 1024 + (size_t)jg * 32 + 16 + il] = hlo;
        Cp[prow * 512 + jglob] = cn;
    }
}

// ---------------- out[b][c] = sum_d h_root[b][d] * W_out[d][c] ----------------
__global__ __launch_bounds__(256)
void out_kernel(const u16* __restrict__ Hroot, const float* __restrict__ W_out,
                float* __restrict__ out)
{
    const int b = blockIdx.x;
    const int tid = threadIdx.x;
    float s0 = 0.f, s1 = 0.f;
    for (int d = tid; d < 512; d += 256) {
        const u16* row = Hroot + (size_t)b * 1024 + (d >> 4) * 32 + (d & 15);
        float h = bf2f(row[0]) + bf2f(row[16]);
        s0 = fmaf(h, W_out[d * 2 + 0], s0);
        s1 = fmaf(h, W_out[d * 2 + 1], s1);
    }
#pragma unroll
    for (int off = 32; off > 0; off >>= 1) {
        s0 += __shfl_down(s0, off, 64);
        s1 += __shfl_down(s1, off, 64);
    }
    __shared__ float red[2][4];
    const int wave = tid >> 6;
    if ((tid & 63) == 0) { red[0][wave] = s0; red[1][wave] = s1; }
    __syncthreads();
    if (tid == 0) {
        float t0 = 0.f, t1 = 0.f;
#pragma unroll
        for (int wv = 0; wv < 4; wv++) { t0 += red[0][wv]; t1 += red[1][wv]; }
        out[b * 2 + 0] = t0;
        out[b * 2 + 1] = t1;
    }
}

extern "C" void kernel_launch(void* const* d_in, const int* in_sizes, int n_in,
                              void* d_out, int out_size, void* d_ws, size_t ws_size,
                              hipStream_t stream)
{
    const int*   tokens = (const int*)  d_in[0];
    const float* emb    = (const float*)d_in[1];
    const float* W_iou  = (const float*)d_in[2];
    const float* b_iou  = (const float*)d_in[3];
    const float* W_f    = (const float*)d_in[4];
    const float* b_f    = (const float*)d_in[5];
    const float* W_out  = (const float*)d_in[6];
    float* out = (float*)d_out;

    // ws layout (201.3 MB, proven):
    u16*   H0 = (u16*)d_ws;
    float* C0 = (float*)(H0 + (size_t)512 * 64 * 1024);
    u16*   H1 = (u16*)(C0 + (size_t)512 * 64 * 512);
    float* C1 = (float*)(H1 + (size_t)256 * 64 * 1024);

    wsplit_kernel<<<dim3(32, 40), 256, 0, stream>>>(W_iou, W_f);
    leafgather_kernel<<<8192, 256, 0, stream>>>(tokens, emb);

    // level 9: leaves -> 512 parents (A = g_Aleaf, c = 0)
    level_big<true><<<dim3(8, 512), 256, 0, stream>>>(
        nullptr, nullptr, b_iou, b_f, H0, C0, 512, 9);

    u16* Hc = H0;  float* Cc = C0;
    u16* Hp = H1;  float* Cp = C1;
    for (int L = 8; L >= 0; L--) {
        const int np = 1 << L;
        if (np >= 64) {
            level_big<false><<<dim3(8, np), 256, 0, stream>>>(
                Hc, Cc, b_iou, b_f, Hp, Cp, np, L);
        } else {
            level_small2<<<dim3(32, np), 256, 0, stream>>>(
                Hc, Cc, b_iou, b_f, Hp, Cp, np, L);
        }
        u16* tH = Hc; Hc = Hp; Hp = tH;
        float* tC = Cc; Cc = Cp; Cp = tC;
    }

    out_kernel<<<64, 256, 0, stream>>>(Hc, W_out, out);
}

// Round 20
// 1177.406 us; speedup vs baseline: 1.1738x; 1.1312x over previous
//
#include <hip/hip_runtime.h>
#include <math.h>

typedef unsigned short u16;
typedef short s16x8 __attribute__((ext_vector_type(8)));
typedef float f32x4 __attribute__((ext_vector_type(4)));

#define NITER 32   // K=1024 / BK=32 k-tiles

// Pre-split, transposed weights: layout [kb 32][gate 5][j 512][k 32]
__device__ __align__(16) u16 g_Bhi[1024 * 2560];
__device__ __align__(16) u16 g_Blo[1024 * 2560];
// Pre-split leaf A panel: row i -> split emb[tokens[i]] (1024 u16 = 32 chunks of [16hi|16lo])
__device__ __align__(16) u16 g_Aleaf[(size_t)64 * 1024 * 1024];

__device__ __forceinline__ u16 f2bf(float x) {
    unsigned u = __float_as_uint(x);
    u += 0x7fffu + ((u >> 16) & 1u);       // RNE
    return (u16)(u >> 16);
}
__device__ __forceinline__ float bf2f(u16 h) { return __uint_as_float(((unsigned)h) << 16); }
__device__ __forceinline__ float sigm(float x) { return 1.0f / (1.0f + expf(-x)); }
__device__ __forceinline__ unsigned pk(u16 a, u16 b) { return (unsigned)a | ((unsigned)b << 16); }

// Default cache policy: R18 (NT stores) and R19 (NT loads) both REGRESSED —
// A is reused 8x across j-group blocks, so L2 caching of A is beneficial.
__device__ __forceinline__ void gload16(const void* g, u16* l) {
    __builtin_amdgcn_global_load_lds(
        (const __attribute__((address_space(1))) void*)g,
        (__attribute__((address_space(3))) void*)(void*)l, 16, 0, 0);
}

// ---------------- weight split+transpose: W[k][col] f32 -> [kb][g][j][k] bf16 hi/lo ----------
__global__ __launch_bounds__(256)
void wsplit_kernel(const float* __restrict__ Wiou, const float* __restrict__ Wf)
{
    __shared__ float tile[32][65];
    const int kb = blockIdx.x;           // 0..31
    const int cb = blockIdx.y;           // 0..39
    const int t  = threadIdx.x;
    const int c0 = cb * 64;

    {
        const int kk  = t >> 3;
        const int cu0 = (t & 7) * 8;
        const int k   = kb * 32 + kk;
#pragma unroll
        for (int u = 0; u < 8; u++) {
            int c = c0 + cu0 + u;
            float v = (c < 1536) ? Wiou[(size_t)k * 1536 + c]
                                 : Wf[(size_t)k * 1024 + (c - 1536)];
            tile[kk][cu0 + u] = v;
        }
    }
    __syncthreads();
    {
        const int jl = t >> 2;
        const int kc = (t & 3) * 8;
        const int g  = c0 >> 9;
        const int j  = (c0 & 511) + jl;
        size_t dst = (((size_t)kb * 5 + g) * 512 + j) * 32 + kc;
        unsigned ph[4], pl[4];
#pragma unroll
        for (int u = 0; u < 4; u++) {
            float v0 = tile[kc + 2 * u][jl];
            float v1 = tile[kc + 2 * u + 1][jl];
            u16 h0 = f2bf(v0), h1 = f2bf(v1);
            u16 l0 = f2bf(v0 - bf2f(h0)), l1 = f2bf(v1 - bf2f(h1));
            ph[u] = pk(h0, h1);
            pl[u] = pk(l0, l1);
        }
        *(uint4*)(g_Bhi + dst) = make_uint4(ph[0], ph[1], ph[2], ph[3]);
        *(uint4*)(g_Blo + dst) = make_uint4(pl[0], pl[1], pl[2], pl[3]);
    }
}

// ---------------- leaf A gather+split ----------------
__global__ __launch_bounds__(256)
void leafgather_kernel(const int* __restrict__ tokens, const float* __restrict__ emb)
{
    const int gidx = blockIdx.x * 256 + threadIdx.x;   // chunk id
    const int row  = gidx >> 5;
    const int c    = gidx & 31;
    const int tok  = tokens[row];
    const float* src = emb + (size_t)tok * 512 + c * 16;
    u16* dst = g_Aleaf + (size_t)row * 1024 + c * 32;

    float4 f0 = *(const float4*)(src);
    float4 f1 = *(const float4*)(src + 4);
    float4 f2 = *(const float4*)(src + 8);
    float4 f3 = *(const float4*)(src + 12);
    float v[16] = {f0.x,f0.y,f0.z,f0.w, f1.x,f1.y,f1.z,f1.w,
                   f2.x,f2.y,f2.z,f2.w, f3.x,f3.y,f3.z,f3.w};
    unsigned ph[8], pl[8];
#pragma unroll
    for (int i = 0; i < 8; i++) {
        u16 h0 = f2bf(v[2*i]),   h1 = f2bf(v[2*i+1]);
        u16 l0 = f2bf(v[2*i]   - bf2f(h0));
        u16 l1 = f2bf(v[2*i+1] - bf2f(h1));
        ph[i] = pk(h0, h1);
        pl[i] = pk(l0, l1);
    }
    *(uint4*)(dst)      = make_uint4(ph[0], ph[1], ph[2], ph[3]);
    *(uint4*)(dst + 8)  = make_uint4(ph[4], ph[5], ph[6], ph[7]);
    *(uint4*)(dst + 16) = make_uint4(pl[0], pl[1], pl[2], pl[3]);
    *(uint4*)(dst + 24) = make_uint4(pl[4], pl[5], pl[6], pl[7]);
}

// ---------------- big levels (np>=64): R16 kernel (proven best) ----------------
template<bool LEAF>
__global__ __launch_bounds__(256, 2)
void level_big(const u16* __restrict__ Hcin, const float* __restrict__ Cc,
               const float* __restrict__ b_iou, const float* __restrict__ b_f,
               u16* __restrict__ Hp, float* __restrict__ Cp,
               int np, int lgnp)
{
    __shared__ __align__(16) u16 Ab0[8192];   // 16 KB: k-tiles {t0, t0+1}
    __shared__ __align__(16) u16 Ab1[8192];   // 16 KB: next window

    const u16* Hc = LEAF ? g_Aleaf : Hcin;

    const int tid = threadIdx.x;
    const int jg  = blockIdx.x;          // 0..7 -> XCD pinning via %8
    const int m0  = blockIdx.y * 64;
    const int j0  = jg * 64;
    const int nc  = np * 2;

    const int w    = tid >> 6;
    const int lane = tid & 63;
    const int il   = lane & 15;
    const int kq   = lane >> 4;
    const int wc   = w;                  // j sub-range wc*16 .. +15

    f32x4 acc[4][5];
#pragma unroll
    for (int rf = 0; rf < 4; rf++)
#pragma unroll
        for (int g = 0; g < 5; g++) acc[rf][g] = (f32x4)0.0f;

    const int bA  = m0 >> lgnp;
    const int pA0 = m0 & (np - 1);
    const char* A0u = (const char*)(Hc + ((size_t)bA * nc + 2 * pA0) * 1024);  // uniform
    const int rowS = tid >> 3;
    const int segS = (tid & 7) ^ (rowS & 7);
    const unsigned voffA = (unsigned)rowS * 4096u + (unsigned)segS * 16u;

    const int shi = ((kq >> 1) << 2) | (kq & 1);
    const int x7  = il & 7;
    const int aoh = il * 64 + ((shi ^ x7) * 8);
    const int aol = il * 64 + (((shi + 2) ^ x7) * 8);

    const char* BH0 = (const char*)(g_Bhi + (size_t)j0 * 32);
    const char* BL0 = (const char*)(g_Blo + (size_t)j0 * 32);
    unsigned vB[5];
#pragma unroll
    for (int g = 0; g < 5; g++)
        vB[g] = (unsigned)(((wc * 16 + il) * 32 + kq * 8) * 2 + g * 32768);

    s16x8 bh[5], bl[5];
    s16x8 ah[4], al[4];

#define STAGEA2(DST, t_)                                                       \
    {                                                                          \
        const char* ab = A0u + (size_t)(t_) * 128;                             \
        gload16(ab + voffA, (DST) + w * 512);                                  \
        gload16(ab + 131072 + voffA, (DST) + 2048 + w * 512);                  \
    }

#define LOADB_HI(t_)                                                           \
    {                                                                          \
        const char* bhp = BH0 + (size_t)(t_) * 163840;                         \
        _Pragma("unroll")                                                      \
        for (int g = 0; g < 5; g++) bh[g] = *(const s16x8*)(bhp + vB[g]);      \
    }

#define LOADB_LO(t_)                                                           \
    {                                                                          \
        const char* blp = BL0 + (size_t)(t_) * 163840;                         \
        _Pragma("unroll")                                                      \
        for (int g = 0; g < 5; g++) bl[g] = *(const s16x8*)(blp + vB[g]);      \
    }

#define READ_AH(ABASE)                                                         \
    {                                                                          \
        _Pragma("unroll")                                                      \
        for (int rf = 0; rf < 4; rf++)                                         \
            ah[rf] = *(const s16x8*)&(ABASE)[aoh + rf * 1024];                 \
    }

#define READ_AL(ABASE)                                                         \
    {                                                                          \
        _Pragma("unroll")                                                      \
        for (int rf = 0; rf < 4; rf++)                                         \
            al[rf] = *(const s16x8*)&(ABASE)[aol + rf * 1024];                 \
    }

#define MFMA_PASS(AREGS, BSET)                                                 \
    {                                                                          \
        __builtin_amdgcn_s_setprio(1);                                         \
        _Pragma("unroll")                                                      \
        for (int rf = 0; rf < 4; rf++)                                         \
            _Pragma("unroll")                                                  \
            for (int g = 0; g < 5; g++)                                        \
                acc[rf][g] = __builtin_amdgcn_mfma_f32_16x16x32_bf16(AREGS[rf], BSET[g], acc[rf][g], 0, 0, 0); \
        __builtin_amdgcn_s_setprio(0);                                         \
    }

#define WINDOW(ACUR, ANXT, t0_, more_)                                         \
    {                                                                          \
        if (more_) {                                                           \
            STAGEA2(ANXT, (t0_) + 2);                                          \
            STAGEA2((ANXT) + 4096, (t0_) + 3);                                 \
            __builtin_amdgcn_sched_barrier(0);                                 \
        }                                                                      \
        MFMA_PASS(ah, bh);                                                     \
        MFMA_PASS(al, bh);                                                     \
        LOADB_HI((t0_) + 1);                                                   \
        READ_AL((ACUR) + 4096);                                                \
        MFMA_PASS(ah, bl);                                                     \
        LOADB_LO((t0_) + 1);                                                   \
        READ_AH((ACUR) + 4096);                                                \
        MFMA_PASS(al, bh);                                                     \
        MFMA_PASS(ah, bh);                                                     \
        if (more_) LOADB_HI((t0_) + 2);                                        \
        MFMA_PASS(ah, bl);                                                     \
        if (more_) LOADB_LO((t0_) + 2);                                        \
        if (more_) {                                                           \
            asm volatile("s_waitcnt vmcnt(10)" ::: "memory");                  \
            __builtin_amdgcn_s_barrier();                                      \
            __builtin_amdgcn_sched_barrier(0);                                 \
            READ_AH(ANXT);                                                     \
            READ_AL(ANXT);                                                     \
        }                                                                      \
    }

    STAGEA2(Ab0, 0);
    STAGEA2(Ab0 + 4096, 1);
    __builtin_amdgcn_sched_barrier(0);
    LOADB_HI(0);
    LOADB_LO(0);
    asm volatile("s_waitcnt vmcnt(10)" ::: "memory");
    __builtin_amdgcn_s_barrier();
    __builtin_amdgcn_sched_barrier(0);
    READ_AH(Ab0);
    READ_AL(Ab0);

#pragma unroll 1
    for (int t0 = 0; t0 < NITER; t0 += 4) {
        WINDOW(Ab0, Ab1, t0, 1);
        WINDOW(Ab1, Ab0, t0 + 2, (t0 + 4 < NITER));
    }
#undef STAGEA2
#undef LOADB_HI
#undef LOADB_LO
#undef READ_AH
#undef READ_AL
#undef MFMA_PASS
#undef WINDOW

    const int jglob = j0 + wc * 16 + il;
    const float bi  = b_iou[jglob];
    const float bo_ = b_iou[512 + jglob];
    const float bu  = b_iou[1024 + jglob];
    const float bfl = b_f[jglob];
    const float bfr = b_f[512 + jglob];

#pragma unroll
    for (int rf = 0; rf < 4; rf++) {
#pragma unroll
        for (int r = 0; r < 4; r++) {
            const int m  = m0 + rf * 16 + kq * 4 + r;
            const int b  = m >> lgnp;
            const int p  = m & (np - 1);
            float i_ = acc[rf][0][r] + bi;
            float o_ = acc[rf][1][r] + bo_;
            float u_ = acc[rf][2][r] + bu;
            float fl = sigm(acc[rf][3][r] + bfl);
            float fr = sigm(acc[rf][4][r] + bfr);
            float cl = 0.0f, cr_ = 0.0f;
            if (!LEAF) {
                size_t cb_ = ((size_t)b * nc + 2 * p) * 512 + jglob;
                cl  = Cc[cb_];
                cr_ = Cc[cb_ + 512];
            }
            float cn = sigm(i_) * tanhf(u_) + fl * cl + fr * cr_;
            float hn = sigm(o_) * tanhf(cn);
            size_t prow = (size_t)b * np + p;
            u16 hh  = f2bf(hn);
            u16 hlo = f2bf(hn - bf2f(hh));
            Hp[prow * 1024 + (size_t)(jg * 4 + wc) * 32 + il]      = hh;
            Hp[prow * 1024 + (size_t)(jg * 4 + wc) * 32 + 16 + il] = hlo;
            Cp[prow * 512 + jglob] = cn;
        }
    }
}

// ---------------- small levels (np<64): 32 j-groups x 16 j, waves split rows -------------
__global__ __launch_bounds__(256, 2)
void level_small2(const u16* __restrict__ Hc, const float* __restrict__ Cc,
                  const float* __restrict__ b_iou, const float* __restrict__ b_f,
                  u16* __restrict__ Hp, float* __restrict__ Cp,
                  int np, int lgnp)
{
    __shared__ __align__(16) u16 Ab0[8192];
    __shared__ __align__(16) u16 Ab1[8192];

    const int tid = threadIdx.x;
    const int jg  = blockIdx.x;          // 0..31, one 16-d chunk; XCD = jg % 8
    const int m0  = blockIdx.y * 64;
    const int j0  = jg * 16;
    const int nc  = np * 2;

    const int w    = tid >> 6;           // wave -> row quarter
    const int lane = tid & 63;
    const int il   = lane & 15;
    const int kq   = lane >> 4;

    f32x4 acc[5];
#pragma unroll
    for (int g = 0; g < 5; g++) acc[g] = (f32x4)0.0f;

    const char* A0u = (const char*)(Hc + (size_t)m0 * 2048);   // globally contiguous rows
    const int rowS = tid >> 3;
    const int segS = (tid & 7) ^ (rowS & 7);
    const unsigned voffA = (unsigned)rowS * 4096u + (unsigned)segS * 16u;

    const int shi = ((kq >> 1) << 2) | (kq & 1);
    const int x7  = il & 7;
    const int aoh = (w * 16 + il) * 64 + ((shi ^ x7) * 8);
    const int aol = (w * 16 + il) * 64 + (((shi + 2) ^ x7) * 8);

    const char* BH0 = (const char*)(g_Bhi + (size_t)j0 * 32);
    const char* BL0 = (const char*)(g_Blo + (size_t)j0 * 32);
    unsigned vB[5];
#pragma unroll
    for (int g = 0; g < 5; g++)
        vB[g] = (unsigned)((il * 32 + kq * 8) * 2 + g * 32768);

    s16x8 bh[5], bl[5];
    s16x8 ah, al;

#define SSTAGEA2(DST, t_)                                                      \
    {                                                                          \
        const char* ab = A0u + (size_t)(t_) * 128;                             \
        gload16(ab + voffA, (DST) + w * 512);                                  \
        gload16(ab + 131072 + voffA, (DST) + 2048 + w * 512);                  \
    }

#define SLOADB_HI(t_)                                                          \
    {                                                                          \
        const char* bhp = BH0 + (size_t)(t_) * 163840;                         \
        _Pragma("unroll")                                                      \
        for (int g = 0; g < 5; g++) bh[g] = *(const s16x8*)(bhp + vB[g]);      \
    }

#define SLOADB_LO(t_)                                                          \
    {                                                                          \
        const char* blp = BL0 + (size_t)(t_) * 163840;                         \
        _Pragma("unroll")                                                      \
        for (int g = 0; g < 5; g++) bl[g] = *(const s16x8*)(blp + vB[g]);      \
    }

#define SREAD_AH(ABASE)  { ah = *(const s16x8*)&(ABASE)[aoh]; }
#define SREAD_AL(ABASE)  { al = *(const s16x8*)&(ABASE)[aol]; }

#define SMFMA_PASS(AREG, BSET)                                                 \
    {                                                                          \
        _Pragma("unroll")                                                      \
        for (int g = 0; g < 5; g++)                                            \
            acc[g] = __builtin_amdgcn_mfma_f32_16x16x32_bf16(AREG, BSET[g], acc[g], 0, 0, 0); \
    }

#define SWINDOW(ACUR, ANXT, t0_, more_)                                        \
    {                                                                          \
        if (more_) {                                                           \
            SSTAGEA2(ANXT, (t0_) + 2);                                         \
            SSTAGEA2((ANXT) + 4096, (t0_) + 3);                                \
            __builtin_amdgcn_sched_barrier(0);                                 \
        }                                                                      \
        SMFMA_PASS(ah, bh);                                                    \
        SMFMA_PASS(al, bh);                                                    \
        SLOADB_HI((t0_) + 1);                                                  \
        SREAD_AL((ACUR) + 4096);                                               \
        SMFMA_PASS(ah, bl);                                                    \
        SLOADB_LO((t0_) + 1);                                                  \
        SREAD_AH((ACUR) + 4096);                                               \
        SMFMA_PASS(al, bh);                                                    \
        SMFMA_PASS(ah, bh);                                                    \
        if (more_) SLOADB_HI((t0_) + 2);                                       \
        SMFMA_PASS(ah, bl);                                                    \
        if (more_) SLOADB_LO((t0_) + 2);                                       \
        if (more_) {                                                           \
            asm volatile("s_waitcnt vmcnt(10)" ::: "memory");                  \
            __builtin_amdgcn_s_barrier();                                      \
            __builtin_amdgcn_sched_barrier(0);                                 \
            SREAD_AH(ANXT);                                                    \
            SREAD_AL(ANXT);                                                    \
        }                                                                      \
    }

    SSTAGEA2(Ab0, 0);
    SSTAGEA2(Ab0 + 4096, 1);
    __builtin_amdgcn_sched_barrier(0);
    SLOADB_HI(0);
    SLOADB_LO(0);
    asm volatile("s_waitcnt vmcnt(10)" ::: "memory");
    __builtin_amdgcn_s_barrier();
    __builtin_amdgcn_sched_barrier(0);
    SREAD_AH(Ab0);
    SREAD_AL(Ab0);

#pragma unroll 1
    for (int t0 = 0; t0 < NITER; t0 += 4) {
        SWINDOW(Ab0, Ab1, t0, 1);
        SWINDOW(Ab1, Ab0, t0 + 2, (t0 + 4 < NITER));
    }
#undef SSTAGEA2
#undef SLOADB_HI
#undef SLOADB_LO
#undef SREAD_AH
#undef SREAD_AL
#undef SMFMA_PASS
#undef SWINDOW

    // ---- fused LSTM epilogue ----
    const int jglob = j0 + il;
    const float bi  = b_iou[jglob];
    const float bo_ = b_iou[512 + jglob];
    const float bu  = b_iou[1024 + jglob];
    const float bfl = b_f[jglob];
    const float bfr = b_f[512 + jglob];

#pragma unroll
    for (int r = 0; r < 4; r++) {
        const int m = m0 + w * 16 + kq * 4 + r;
        const int b = m >> lgnp;
        const int p = m & (np - 1);
        float i_ = acc[0][r] + bi;
        float o_ = acc[1][r] + bo_;
        float u_ = acc[2][r] + bu;
        float fl = sigm(acc[3][r] + bfl);
        float fr = sigm(acc[4][r] + bfr);
        size_t cb_ = ((size_t)b * nc + 2 * p) * 512 + jglob;
        float cl  = Cc[cb_];
        float cr_ = Cc[cb_ + 512];
        float cn = sigm(i_) * tanhf(u_) + fl * cl + fr * cr_;
        float hn = sigm(o_) * tanhf(cn);
        size_t prow = (size_t)b * np + p;
        u16 hh  = f2bf(hn);
        u16 hlo = f2bf(hn - bf2f(hh));
        Hp[prow * 1024 + (size_t)jg * 32 + il]      = hh;
        Hp[prow * 1024 + (size_t)jg * 32 + 16 + il] = hlo;
        Cp[prow * 512 + jglob] = cn;
    }
}

// ---------------- out[b][c] = sum_d h_root[b][d] * W_out[d][c] ----------------
__global__ __launch_bounds__(256)
void out_kernel(const u16* __restrict__ Hroot, const float* __restrict__ W_out,
                float* __restrict__ out)
{
    const int b = blockIdx.x;
    const int tid = threadIdx.x;
    float s0 = 0.f, s1 = 0.f;
    for (int d = tid; d < 512; d += 256) {
        const u16* row = Hroot + (size_t)b * 1024 + (d >> 4) * 32 + (d & 15);
        float h = bf2f(row[0]) + bf2f(row[16]);
        s0 = fmaf(h, W_out[d * 2 + 0], s0);
        s1 = fmaf(h, W_out[d * 2 + 1], s1);
    }
#pragma unroll
    for (int off = 32; off > 0; off >>= 1) {
        s0 += __shfl_down(s0, off, 64);
        s1 += __shfl_down(s1, off, 64);
    }
    __shared__ float red[2][4];
    const int wave = tid >> 6;
    if ((tid & 63) == 0) { red[0][wave] = s0; red[1][wave] = s1; }
    __syncthreads();
    if (tid == 0) {
        float t0 = 0.f, t1 = 0.f;
#pragma unroll
        for (int wv = 0; wv < 4; wv++) { t0 += red[0][wv]; t1 += red[1][wv]; }
        out[b * 2 + 0] = t0;
        out[b * 2 + 1] = t1;
    }
}

extern "C" void kernel_launch(void* const* d_in, const int* in_sizes, int n_in,
                              void* d_out, int out_size, void* d_ws, size_t ws_size,
                              hipStream_t stream)
{
    const int*   tokens = (const int*)  d_in[0];
    const float* emb    = (const float*)d_in[1];
    const float* W_iou  = (const float*)d_in[2];
    const float* b_iou  = (const float*)d_in[3];
    const float* W_f    = (const float*)d_in[4];
    const float* b_f    = (const float*)d_in[5];
    const float* W_out  = (const float*)d_in[6];
    float* out = (float*)d_out;

    // ws layout (201.3 MB, proven):
    u16*   H0 = (u16*)d_ws;
    float* C0 = (float*)(H0 + (size_t)512 * 64 * 1024);
    u16*   H1 = (u16*)(C0 + (size_t)512 * 64 * 512);
    float* C1 = (float*)(H1 + (size_t)256 * 64 * 1024);

    wsplit_kernel<<<dim3(32, 40), 256, 0, stream>>>(W_iou, W_f);
    leafgather_kernel<<<8192, 256, 0, stream>>>(tokens, emb);

    // level 9: leaves -> 512 parents (A = g_Aleaf, c = 0)
    level_big<true><<<dim3(8, 512), 256, 0, stream>>>(
        nullptr, nullptr, b_iou, b_f, H0, C0, 512, 9);

    u16* Hc = H0;  float* Cc = C0;
    u16* Hp = H1;  float* Cp = C1;
    for (int L = 8; L >= 0; L--) {
        const int np = 1 << L;
        if (np >= 64) {
            level_big<false><<<dim3(8, np), 256, 0, stream>>>(
                Hc, Cc, b_iou, b_f, Hp, Cp, np, L);
        } else {
            level_small2<<<dim3(32, np), 256, 0, stream>>>(
                Hc, Cc, b_iou, b_f, Hp, Cp, np, L);
        }
        u16* tH = Hc; Hc = Hp; Hp = tH;
        float* tC = Cc; Cc = Cp; Cp = tC;
    }

    out_kernel<<<64, 256, 0, stream>>>(Hc, W_out, out);
}